// Round 13
// baseline (104.516 us; speedup 1.0000x reference)
//
#include <hip/hip_runtime.h>
#include <hip/hip_fp16.h>
#include <stdint.h>

// ---------------------------------------------------------------------------
// CIN block: 3 layers of out[b,k,d] = relu(sum_ij h[b,i,d] feat[b,j,d] W[k,i,j] + b[k])
// R12: FUSED 3-layer kernel. The chain is independent per m=(b,d): each block
// owns a 64-row m-tile through L0->L1->L2; h passes via LDS (no global
// round-trip, no inter-layer launches/drains). W streamed once per CU per
// layer through a 2x64KB LDS ping-pong (4-i-slice chunks): per chunk
// [vmcnt(0) on chunk-old stage][barrier][stage next chunk][h b64][8 ds_read
// b128][16 MFMA]. Last chunk of layer l stages chunk 0 of layer l+1.
// Wave = 64m x 32k (kg = w), 4 independent MFMA chains, 32x32x16.
// Epilogue per layer: bias+relu, h-pairs -> LDS (waves 0-3), d-reduce shfl,
// direct f32x4 out stores. Grid 256 x 512 thr, LDS 144KB, 1 block/CU.
// ---------------------------------------------------------------------------

typedef _Float16 half8_t __attribute__((ext_vector_type(8)));
typedef float f32x4 __attribute__((ext_vector_type(4)));
typedef float f32x16 __attribute__((ext_vector_type(16)));
typedef uint32_t u32x4 __attribute__((ext_vector_type(4)));

union H8 {
  half8_t h;
  uint32_t u[4];
  u32x4 q;
};

#define AS1 __attribute__((address_space(1)))
#define AS3 __attribute__((address_space(3)))

static __device__ __forceinline__ uint32_t pkmul(uint32_t x, uint32_t y) {
  __half2 a = __builtin_bit_cast(__half2, x);
  __half2 b = __builtin_bit_cast(__half2, y);
  __half2 r = __hmul2(a, b);
  return __builtin_bit_cast(uint32_t, r);
}

static __device__ __forceinline__ uint32_t pack2h(float a, float b) {
  __half2 r = __floats2half2_rn(a, b);
  return __builtin_bit_cast(uint32_t, r);
}

// ---- fused prep -------------------------------------------------------------
// W [k][i][j] f32 -> Wt slices [i][16 kt][4 g][16 kr][8 f16] (16KB per i)
// blocks [0,128): W0 ; [128,640): W1 ; [640,1152): W2
// blocks [1152,1216): feat -> F16 [m][32 j] f16, hL0 [mt][16 i2][32 l][2 mbh]
__global__ void prep_kernel(const float* __restrict__ W0, const float* __restrict__ W1,
                            const float* __restrict__ W2, const float* __restrict__ feat,
                            uint16_t* __restrict__ Wt0, uint16_t* __restrict__ Wt1,
                            uint16_t* __restrict__ Wt2,
                            uint16_t* __restrict__ F16, uint32_t* __restrict__ hL0) {
  int blk = blockIdx.x;
  if (blk < 1152) {
    const float* W; uint16_t* Wt; int FLsh, base;
    if (blk < 128)      { W = W0; Wt = Wt0; FLsh = 5; base = 0; }
    else if (blk < 640) { W = W1; Wt = Wt1; FLsh = 7; base = 128; }
    else                { W = W2; Wt = Wt2; FLsh = 7; base = 640; }
    int idx4 = (blk - base) * 256 + threadIdx.x;
    int jg = idx4 & 3;
    int i = (idx4 >> 2) & ((1 << FLsh) - 1);
    int k = idx4 >> (2 + FLsh);
    const float* src = W + ((size_t)(k << FLsh) + i) * 32 + jg * 8;
    float4 x0 = *(const float4*)(src);
    float4 x1 = *(const float4*)(src + 4);
    u32x4 o;
    o[0] = pack2h(x0.x, x0.y);
    o[1] = pack2h(x0.z, x0.w);
    o[2] = pack2h(x1.x, x1.y);
    o[3] = pack2h(x1.z, x1.w);
    int kr = k & 15, kt = k >> 4;
    *(u32x4*)((uint32_t*)Wt + (((size_t)i * 16 + kt) * 64 + jg * 16 + kr) * 4) = o;
  } else {
    int m = (blk - 1152) * 256 + threadIdx.x;  // 0..16383
    int b = m >> 5, d = m & 31;
    const float* fb = feat + (size_t)b * 1024 + d;
    uint16_t hs[32];
#pragma unroll
    for (int j = 0; j < 32; ++j)
      hs[j] = __half_as_ushort(__float2half(fb[j * 32]));
    int mt = m >> 6, mbh = (m >> 5) & 1, ml = m & 31;
#pragma unroll
    for (int i2 = 0; i2 < 16; ++i2) {
      uint32_t pr = (uint32_t)hs[2 * i2] | ((uint32_t)hs[2 * i2 + 1] << 16);
      hL0[(size_t)mt * 1024 + i2 * 64 + ml * 2 + mbh] = pr;
    }
#pragma unroll
    for (int c = 0; c < 4; ++c) {
      u32x4 q;
      q[0] = (uint32_t)hs[c * 8 + 0] | ((uint32_t)hs[c * 8 + 1] << 16);
      q[1] = (uint32_t)hs[c * 8 + 2] | ((uint32_t)hs[c * 8 + 3] << 16);
      q[2] = (uint32_t)hs[c * 8 + 4] | ((uint32_t)hs[c * 8 + 5] << 16);
      q[3] = (uint32_t)hs[c * 8 + 6] | ((uint32_t)hs[c * 8 + 7] << 16);
      *(u32x4*)(F16 + (size_t)m * 32 + c * 8) = q;
    }
  }
}

// ---- one CIN layer (called from the fused kernel) ---------------------------
template <int NCHK, bool PRODH>
__device__ __forceinline__ void cin_layer(
    const char* wlay, const char* wnext, const float* __restrict__ bias,
    float* __restrict__ outp, int obase, int klo,
    char* hlds, char* ring0, char* ring1,
    int tid, int w, int l31, int l5, int lane, int mt,
    const H8& ffA0, const H8& ffA1, const H8& ffB0, const H8& ffB1) {
  f32x16 accA0 = {}, accA1 = {}, accB0 = {}, accB1 = {};
  char* rcur = ring0;
  char* rnxt = ring1;
  const int rboff = w * 2048 + ((l31 >> 4) << 10) + (l5 << 8) + ((l31 & 15) << 4);

#pragma unroll 1
  for (int q = 0; q < NCHK; ++q) {
    // stage(q) (issued one chunk ago) is the only outstanding VMEM: cheap drain
    asm volatile("s_waitcnt vmcnt(0)" ::: "memory");
    __builtin_amdgcn_s_barrier();
    // stage next chunk (or next layer's chunk 0) into the other ring buffer
    const char* src = (q + 1 < NCHK) ? wlay + (size_t)(q + 1) * 65536 : wnext;
#pragma unroll
    for (int c = 0; c < 8; ++c)
      __builtin_amdgcn_global_load_lds(
          (const AS1 uint32_t*)(src + c * 8192 + tid * 16),
          (AS3 uint32_t*)(rnxt + c * 8192 + tid * 16), 16, 0, 0);
    // h pairs for the 4 i-steps of this chunk (broadcast b64 reads)
    uint2 hu0 = *(const uint2*)(hlds + q * 512 + l31 * 8);
    uint2 hu1 = *(const uint2*)(hlds + q * 512 + 256 + l31 * 8);
    const char* rb = rcur + rboff;
#pragma unroll
    for (int s = 0; s < 4; ++s) {
      H8 wf0, wf1;
      wf0.q = *(const u32x4*)(rb + s * 16384);
      wf1.q = *(const u32x4*)(rb + s * 16384 + 512);
      uint32_t hx = (s < 2) ? hu0.x : hu1.x;
      uint32_t hy = (s < 2) ? hu0.y : hu1.y;
      uint32_t psel = (s & 1) ? 0x03020302u : 0x01000100u;
      uint32_t eA = __builtin_amdgcn_perm(hx, hx, psel);
      uint32_t eB = __builtin_amdgcn_perm(hy, hy, psel);
      H8 bA0, bA1, bB0, bB1;
#pragma unroll
      for (int c = 0; c < 4; ++c) {
        bA0.u[c] = pkmul(ffA0.u[c], eA);
        bA1.u[c] = pkmul(ffA1.u[c], eA);
        bB0.u[c] = pkmul(ffB0.u[c], eB);
        bB1.u[c] = pkmul(ffB1.u[c], eB);
      }
      accA0 = __builtin_amdgcn_mfma_f32_32x32x16_f16(wf0.h, bA0.h, accA0, 0, 0, 0);
      accB0 = __builtin_amdgcn_mfma_f32_32x32x16_f16(wf0.h, bB0.h, accB0, 0, 0, 0);
      accA1 = __builtin_amdgcn_mfma_f32_32x32x16_f16(wf1.h, bA1.h, accA1, 0, 0, 0);
      accB1 = __builtin_amdgcn_mfma_f32_32x32x16_f16(wf1.h, bB1.h, accB1, 0, 0, 0);
    }
    char* t = rcur; rcur = rnxt; rnxt = t;
  }

  // ---- epilogue: bias + relu -------------------------------------------------
  f32x16 accA = accA0 + accA1;
  f32x16 accB = accB0 + accB1;
  f32x4 bv[4];
#pragma unroll
  for (int a = 0; a < 4; ++a)
    bv[a] = *(const f32x4*)(bias + w * 32 + a * 8 + l5 * 4);
  float vA[16], vB[16];
#pragma unroll
  for (int a = 0; a < 4; ++a)
#pragma unroll
    for (int t = 0; t < 4; ++t) {
      float x = accA[a * 4 + t] + bv[a][t];
      vA[a * 4 + t] = x > 0.f ? x : 0.f;
      float y = accB[a * 4 + t] + bv[a][t];
      vB[a * 4 + t] = y > 0.f ? y : 0.f;
    }

  // ---- h for next layer -> LDS (k<128 -> waves 0-3) --------------------------
  if (PRODH) {
    __syncthreads();  // all h-reads of this layer done before overwrite
    if (w < 4) {
#pragma unroll
      for (int a = 0; a < 4; ++a)
#pragma unroll
        for (int c = 0; c < 2; ++c) {
          int i2 = w * 16 + 4 * a + 2 * l5 + c;
          uint2 pr;
          pr.x = pack2h(vA[a * 4 + 2 * c], vA[a * 4 + 2 * c + 1]);
          pr.y = pack2h(vB[a * 4 + 2 * c], vB[a * 4 + 2 * c + 1]);
          *(uint2*)(hlds + i2 * 256 + l31 * 8) = pr;
        }
    }
  }

  // ---- d-reduction + direct output ------------------------------------------
#pragma unroll
  for (int r = 0; r < 16; ++r) {
    float x = vA[r];
    x += __shfl_xor(x, 1); x += __shfl_xor(x, 2);
    x += __shfl_xor(x, 4); x += __shfl_xor(x, 8);
    x += __shfl_xor(x, 16);
    vA[r] = x;
    float y = vB[r];
    y += __shfl_xor(y, 1); y += __shfl_xor(y, 2);
    y += __shfl_xor(y, 4); y += __shfl_xor(y, 8);
    y += __shfl_xor(y, 16);
    vB[r] = y;
  }
  if (w * 32 >= klo && (lane == 0 || lane == 32)) {
    float* obA = outp + (size_t)(mt * 2) * 512 + obase + w * 32 - klo + l5 * 4;
#pragma unroll
    for (int a = 0; a < 4; ++a) {
      *(f32x4*)(obA + a * 8) =
          (f32x4){vA[a * 4], vA[a * 4 + 1], vA[a * 4 + 2], vA[a * 4 + 3]};
      *(f32x4*)(obA + 512 + a * 8) =
          (f32x4){vB[a * 4], vB[a * 4 + 1], vB[a * 4 + 2], vB[a * 4 + 3]};
    }
  }
  if (PRODH) __syncthreads();  // h visible to all waves before next layer
}

// ---- fused 3-layer kernel ---------------------------------------------------
// grid 256 (mt = 64 m-rows), block 512 (8 waves); wave w owns k [32w, 32w+32).
__global__ __launch_bounds__(512, 2) void cin_fused(
    const uint32_t* __restrict__ hL0g,  // [mt][16 i2][32][2] u32 pairs
    const uint16_t* __restrict__ wt0, const uint16_t* __restrict__ wt1,
    const uint16_t* __restrict__ wt2,
    const uint16_t* __restrict__ f16m,  // [16384][32] f16
    const float* __restrict__ b0, const float* __restrict__ b1,
    const float* __restrict__ b2,
    float* __restrict__ outp) {        // [512][512] f32
  __shared__ __align__(16) char smem[147456];  // 16KB h + 2 x 64KB W ring
  char* hlds = smem;
  char* ring0 = smem + 16384;
  char* ring1 = smem + 81920;
  const int tid = threadIdx.x;
  const int lane = tid & 63, w = tid >> 6;
  const int l31 = lane & 31, l5 = lane >> 5;
  const int mt = blockIdx.x;

  // --- prologue: stage h(L0) 4KB + W(L0) chunk 0 into ring0 ---
  if (tid < 256)
    __builtin_amdgcn_global_load_lds(
        (const AS1 uint32_t*)(hL0g + (size_t)mt * 1024 + tid * 4),
        (AS3 uint32_t*)(hlds + tid * 16), 16, 0, 0);
  const char* w0b = (const char*)wt0;
  const char* w1b = (const char*)wt1;
  const char* w2b = (const char*)wt2;
#pragma unroll
  for (int c = 0; c < 8; ++c)
    __builtin_amdgcn_global_load_lds(
        (const AS1 uint32_t*)(w0b + c * 8192 + tid * 16),
        (AS3 uint32_t*)(ring0 + c * 8192 + tid * 16), 16, 0, 0);

  // --- resident F fragments for mb0 = 2mt (A) and mb1 = 2mt+1 (B) ---
  const uint16_t* fb0 = f16m + ((size_t)mt * 64 + l31) * 32 + l5 * 8;
  H8 ffA0, ffA1, ffB0, ffB1;
  ffA0.q = *(const u32x4*)(fb0);
  ffA1.q = *(const u32x4*)(fb0 + 16);
  ffB0.q = *(const u32x4*)(fb0 + 1024);
  ffB1.q = *(const u32x4*)(fb0 + 1040);

  // --- three layers; last chunk of each stages the next layer's chunk 0 ---
  cin_layer<8, true>(w0b, w1b, b0, outp, 0, 128, hlds, ring0, ring1,
                     tid, w, l31, l5, lane, mt, ffA0, ffA1, ffB0, ffB1);
  cin_layer<32, true>(w1b, w2b, b1, outp, 128, 128, hlds, ring0, ring1,
                      tid, w, l31, l5, lane, mt, ffA0, ffA1, ffB0, ffB1);
  cin_layer<32, false>(w2b, w2b, b2, outp, 256, 0, hlds, ring0, ring1,
                       tid, w, l31, l5, lane, mt, ffA0, ffA1, ffB0, ffB1);

  asm volatile("s_waitcnt vmcnt(0)" ::: "memory");  // drain tail LDS-DMA
}

// ---------------------------------------------------------------------------
extern "C" void kernel_launch(void* const* d_in, const int* in_sizes, int n_in,
                              void* d_out, int out_size, void* d_ws, size_t ws_size,
                              hipStream_t stream) {
  const float* feat = (const float*)d_in[0];
  const float* W0 = (const float*)d_in[1];
  const float* b0 = (const float*)d_in[2];
  const float* W1 = (const float*)d_in[3];
  const float* b1 = (const float*)d_in[4];
  const float* W2 = (const float*)d_in[5];
  const float* b2 = (const float*)d_in[6];
  float* out = (float*)d_out;
  char* ws = (char*)d_ws;

  // workspace layout (bytes)
  uint16_t* Wt0 = (uint16_t*)(ws + 0x000000);  // 512KB
  uint16_t* Wt1 = (uint16_t*)(ws + 0x080000);  // 2MB
  uint16_t* Wt2 = (uint16_t*)(ws + 0x280000);  // 2MB
  uint16_t* F16 = (uint16_t*)(ws + 0x480000);  // 1MB
  uint32_t* hL0 = (uint32_t*)(ws + 0x580000);  // [256 mt][1024] u32 = 1MB

  prep_kernel<<<1216, 256, 0, stream>>>(W0, W1, W2, feat, Wt0, Wt1, Wt2, F16, hL0);

  cin_fused<<<256, 512, 0, stream>>>(hL0, Wt0, Wt1, Wt2, F16, b0, b1, b2, out);
}